// Round 1
// baseline (430.291 us; speedup 1.0000x reference)
//
#include <hip/hip_runtime.h>
#include <stdint.h>
#include <math.h>

// ============================================================================
// ProposalDistribution: 4x fp32 GEMM [32768,512]x[512,512]^T -> exp ->
// per-row Gaussian-NLL quadratic coefficients -> JAX-threefry rejection sampler.
//
// R6 -> R7: R6's round schedule was stage -> barrier(vmcnt(0)) -> compute:
// the global_load_lds latency was fully exposed every round (MfmaUtil 29%).
// R7 double-buffers Wp and Xh/Xl (80 KB LDS exactly, still 2 blocks/CU),
// issues round r+1's DMA/X-write at the TOP of round r, computes, and only
// then waits vmcnt(0)+lgkmcnt(0) before a single s_barrier per round
// (guide T3 "minimum 2-phase" template). The red[] LDS double array moved
// to per-lane register accumulators (same double-add order -> bit-identical
// numerics); the final cross-wave exchange reuses Wp storage after the loop.
// ============================================================================

typedef _Float16 f16;
typedef __attribute__((ext_vector_type(8))) _Float16 f16x8;
typedef __attribute__((ext_vector_type(4))) _Float16 f16x4;
typedef __attribute__((ext_vector_type(4))) float f32x4;

#define SX 16.0f
#define SW 1024.0f
#define INV_S (1.0f / 16384.0f)
#define LOG_EPS (-13.815510557964274f)   // log(1e-6)
#define PLANE 262144                      // 512*512 elements per f16 plane
#define WS_NEED (4u * 2u * PLANE * 2u)    // 4 mats x (hi+lo) x 2B = 4 MB

struct U2 { uint32_t a, b; };

__device__ __forceinline__ uint32_t rotl(uint32_t v, int d) {
  return (v << d) | (v >> (32 - d));
}

// Threefry-2x32, 20 rounds — exact JAX algorithm.
__device__ __forceinline__ U2 tf2x32(uint32_t k0, uint32_t k1, uint32_t x0, uint32_t x1) {
  const uint32_t k2 = k0 ^ k1 ^ 0x1BD11BDAu;
  x0 += k0; x1 += k1;
#define TFR(r) { x0 += x1; x1 = rotl(x1, r); x1 ^= x0; }
  TFR(13) TFR(15) TFR(26) TFR(6)
  x0 += k1; x1 += k2 + 1u;
  TFR(17) TFR(29) TFR(16) TFR(24)
  x0 += k2; x1 += k0 + 2u;
  TFR(13) TFR(15) TFR(26) TFR(6)
  x0 += k0; x1 += k1 + 3u;
  TFR(17) TFR(29) TFR(16) TFR(24)
  x0 += k1; x1 += k2 + 4u;
  TFR(13) TFR(15) TFR(26) TFR(6)
  x0 += k2; x1 += k0 + 5u;
#undef TFR
  U2 r; r.a = x0; r.b = x1; return r;
}

__device__ __forceinline__ float bits_to_u01(uint32_t b) {
  return __uint_as_float((b >> 9) | 0x3f800000u) - 1.0f;
}

// ---------------------------------------------------------------------------
// Pre-kernel: split 4 W matrices (fp32, scaled by 1024) into fp16 hi/lo planes.
// ws layout: mat m -> hi plane at m*2*PLANE, lo plane at +PLANE.
// mats: 0=W_mu_x, 1=W_sg_x, 2=W_mu_y, 3=W_sg_y. Row-major [outcol][k].
// ---------------------------------------------------------------------------
__global__ __launch_bounds__(256) void convert_w_kernel(
    const float* __restrict__ w0, const float* __restrict__ w1,
    const float* __restrict__ w2, const float* __restrict__ w3,
    f16* __restrict__ ws)
{
  const int mat = blockIdx.x >> 8;
  const int idx = (((blockIdx.x & 255) << 8) | threadIdx.x) << 2;
  const float* W = (mat == 0) ? w0 : (mat == 1) ? w1 : (mat == 2) ? w2 : w3;
  float4 v = *(const float4*)(W + idx);
  f16* hi = ws + (size_t)mat * (2 * PLANE) + idx;
  f16* lo = hi + PLANE;
  float a0 = v.x * SW, a1 = v.y * SW, a2 = v.z * SW, a3 = v.w * SW;
  f16 h0 = (f16)a0, h1 = (f16)a1, h2 = (f16)a2, h3 = (f16)a3;
  *(f16x4*)hi = (f16x4){h0, h1, h2, h3};
  *(f16x4*)lo = (f16x4){(f16)(a0 - (float)h0), (f16)(a1 - (float)h1),
                        (f16)(a2 - (float)h2), (f16)(a3 - (float)h3)};
}

// swizzled element offset within a [row][32] f16 LDS plane
__device__ __forceinline__ int swz_off(int row, int quad) {
  return row * 32 + ((quad ^ ((row >> 1) & 3)) << 3);
}

// ---------------------------------------------------------------------------
// Main MFMA kernel. 512 blocks x 256 threads (4 waves), 2 blocks/CU.
// Block tile: 64 rows; per round: 128 cols x 32 k, both mats, one dist.
// Rounds ordered dist(2) -> colgroup(4) -> kchunk(16) = 128 rounds.
// Wave w computes cols w*32..+32 (2 col-frags) x 64 rows (4 row-frags).
// Double-buffered: round r stages round r+1's W (DMA) and X, computes round
// r from the other buffer, then one counted-wait barrier per round.
// ---------------------------------------------------------------------------
__global__ __launch_bounds__(256, 2)
void mfma_proposal_kernel(const float* __restrict__ gx, const float* __restrict__ gy,
                          const float* __restrict__ bmux, const float* __restrict__ bsgx,
                          const float* __restrict__ bmuy, const float* __restrict__ bsgy,
                          const f16* __restrict__ ws, float* __restrict__ out)
{
  __shared__ __align__(16) f16 Wp[2][4][128 * 32];  // 64 KB (dbuf x planes)
  __shared__ __align__(16) f16 Xh[2][64 * 32];      // 8 KB
  __shared__ __align__(16) f16 Xl[2][64 * 32];      // 8 KB  -> 80 KB total

  const int tid = threadIdx.x;
  const int lane = tid & 63;
  const int w = tid >> 6;           // wave id
  const int ln = lane & 15;
  const int quad = lane >> 4;
  const int r0 = blockIdx.x * 64;

  const int xrow = tid >> 2;        // 0..63
  const int xs4 = tid & 3;          // global k-seg for X staging
  const int dma_sg = (lane & 3) ^ ((lane >> 3) & 3);  // swizzled global seg for DMA
  const int dma_row = lane >> 2;                       // row within 16-row chunk
  const int xslot = (xs4 ^ ((xrow >> 1) & 3)) << 3;    // swizzled X store slot

  // per-lane double accumulators: lane (quad, ln=ri*4+g) owns row ri*16+quad*4+g
  double dAx = 0, dIx = 0, dMx = 0, dQx = 0;
  double dAy = 0, dIy = 0, dMy = 0, dQy = 0;

  float4 xr0, xr1;

  // stage round n's X-regs from global
  auto load_xr = [&](int n) {
    const float* Xg = (n >> 6) ? gy : gx;
    const float* xp = Xg + (size_t)(r0 + xrow) * 512 + (n & 15) * 32 + xs4 * 8;
    xr0 = *(const float4*)(xp);
    xr1 = *(const float4*)(xp + 4);
  };

  // issue DMA of round n's W tile into Wp[buf]; wave w stages plane w
  auto stage_w = [&](int n, int buf) {
    const int nkc = n & 15, ncg = (n >> 4) & 3, nd = n >> 6;
    const f16* plane = ws + (size_t)(nd * 2 + (w >> 1)) * (2 * PLANE)
                          + (size_t)(w & 1) * PLANE;
    const f16* gp0 = plane + (size_t)(ncg * 128 + dma_row) * 512 + nkc * 32 + dma_sg * 8;
#pragma unroll
    for (int j = 0; j < 8; ++j) {
      __builtin_amdgcn_global_load_lds(
          (const __attribute__((address_space(1))) void*)(gp0 + (size_t)(j * 16) * 512),
          (__attribute__((address_space(3))) void*)&Wp[buf][w][(j * 16) * 32], 16, 0, 0);
    }
  };

  // split-convert xr regs and store into X buffer (swizzled)
  auto write_x = [&](int buf) {
    float a0 = xr0.x * SX, a1 = xr0.y * SX, a2 = xr0.z * SX, a3 = xr0.w * SX;
    float a4 = xr1.x * SX, a5 = xr1.y * SX, a6 = xr1.z * SX, a7 = xr1.w * SX;
    f16 h0 = (f16)a0, h1 = (f16)a1, h2 = (f16)a2, h3 = (f16)a3;
    f16 h4 = (f16)a4, h5 = (f16)a5, h6 = (f16)a6, h7 = (f16)a7;
    *(f16x8*)&Xh[buf][xrow * 32 + xslot] = (f16x8){h0, h1, h2, h3, h4, h5, h6, h7};
    *(f16x8*)&Xl[buf][xrow * 32 + xslot] =
        (f16x8){(f16)(a0 - (float)h0), (f16)(a1 - (float)h1),
                (f16)(a2 - (float)h2), (f16)(a3 - (float)h3),
                (f16)(a4 - (float)h4), (f16)(a5 - (float)h5),
                (f16)(a6 - (float)h6), (f16)(a7 - (float)h7)};
  };

  // ---- prologue: fill buffer 0 for round 0, prefetch xr for round 1 ----
  load_xr(0);
  stage_w(0, 0);
  write_x(0);        // compiler waits vmcnt for xr only; W-DMA stays in flight
  load_xr(1);
  __syncthreads();   // full drain once: W(0) + X(0) visible to all waves

  f32x4 accm[4][2], accv[4][2];

  for (int rid = 0; rid < 128; ++rid) {
    const int cb = rid & 1;
    const int nb = cb ^ 1;
    const int kc = rid & 15;
    const int cg = (rid >> 4) & 3;
    const int dist = rid >> 6;

    if (kc == 0) {
#pragma unroll
      for (int ri = 0; ri < 4; ++ri)
#pragma unroll
        for (int cj = 0; cj < 2; ++cj) {
          accm[ri][cj] = (f32x4)0.0f;
          accv[ri][cj] = (f32x4)0.0f;
        }
    }

    // ---- issue next round's staging FIRST (latency hides under compute) ----
    if (rid + 1 < 128) {
      stage_w(rid + 1, nb);   // 8 global_load_lds, stay in flight through MFMAs
      write_x(nb);            // xr holds round rid+1's data (loaded round rid-1)
    }
    if (rid + 2 < 128) load_xr(rid + 2);

    // ---- compute round rid from buffer cb: 16 ds_read_b128 + 48 MFMA ----
    f16x8 ah[4], al[4];
#pragma unroll
    for (int ri = 0; ri < 4; ++ri) {
      const int off = swz_off(ri * 16 + ln, quad);
      ah[ri] = *(const f16x8*)&Xh[cb][off];
      al[ri] = *(const f16x8*)&Xl[cb][off];
    }
#pragma unroll
    for (int cj = 0; cj < 2; ++cj) {
      const int boff = swz_off(w * 32 + cj * 16 + ln, quad);
      const f16x8 bhm = *(const f16x8*)&Wp[cb][0][boff];
      const f16x8 blm = *(const f16x8*)&Wp[cb][1][boff];
      const f16x8 bhv = *(const f16x8*)&Wp[cb][2][boff];
      const f16x8 blv = *(const f16x8*)&Wp[cb][3][boff];
#pragma unroll
      for (int ri = 0; ri < 4; ++ri) {
        accm[ri][cj] = __builtin_amdgcn_mfma_f32_16x16x32_f16(al[ri], bhm, accm[ri][cj], 0, 0, 0);
        accm[ri][cj] = __builtin_amdgcn_mfma_f32_16x16x32_f16(ah[ri], blm, accm[ri][cj], 0, 0, 0);
        accm[ri][cj] = __builtin_amdgcn_mfma_f32_16x16x32_f16(ah[ri], bhm, accm[ri][cj], 0, 0, 0);
        accv[ri][cj] = __builtin_amdgcn_mfma_f32_16x16x32_f16(al[ri], bhv, accv[ri][cj], 0, 0, 0);
        accv[ri][cj] = __builtin_amdgcn_mfma_f32_16x16x32_f16(ah[ri], blv, accv[ri][cj], 0, 0, 0);
        accv[ri][cj] = __builtin_amdgcn_mfma_f32_16x16x32_f16(ah[ri], bhv, accv[ri][cj], 0, 0, 0);
      }
    }

    // ---- epilogue per (dist, colgroup): fold into per-lane double regs ----
    if (kc == 15) {
      const float* bmu = dist ? bmuy : bmux;
      const float* bsg = dist ? bsgy : bsgx;
      const float bm0 = bmu[cg * 128 + w * 32 + ln];
      const float bm1 = bmu[cg * 128 + w * 32 + 16 + ln];
      const float bv0 = bsg[cg * 128 + w * 32 + ln];
      const float bv1 = bsg[cg * 128 + w * 32 + 16 + ln];
#pragma unroll
      for (int ri = 0; ri < 4; ++ri) {
#pragma unroll
        for (int g = 0; g < 4; ++g) {
          float pA = 0.f, pI = 0.f, pM = 0.f, pQ = 0.f;
#pragma unroll
          for (int cj = 0; cj < 2; ++cj) {
            const float m = accm[ri][cj][g] * INV_S + (cj ? bm1 : bm0);
            const float s = accv[ri][cj][g] * INV_S + (cj ? bv1 : bv0);
            const float vv = fmaxf(expf(s), 1e-6f);
            const float lg = fmaxf(s, LOG_EPS);
            const float iv = __builtin_amdgcn_rcpf(vv);
            pA += lg;
            pI += iv;
            pM += m * iv;
            pQ += m * m * iv;
          }
#pragma unroll
          for (int msk = 1; msk < 16; msk <<= 1) {
            pA += __shfl_xor(pA, msk);
            pI += __shfl_xor(pI, msk);
            pM += __shfl_xor(pM, msk);
            pQ += __shfl_xor(pQ, msk);
          }
          // lane ln == ri*4+g owns row ri*16 + quad*4 + g (same add order as R6)
          if (ln == ri * 4 + g) {
            if (dist == 0) { dAx += pA; dIx += pI; dMx += pM; dQx += pQ; }
            else           { dAy += pA; dIy += pI; dMy += pM; dQy += pQ; }
          }
        }
      }
    }

    // ---- single barrier per round; DMA wait AFTER compute, not before ----
    asm volatile("s_waitcnt vmcnt(0)" ::: "memory");
    asm volatile("s_waitcnt lgkmcnt(0)" ::: "memory");
    __builtin_amdgcn_s_barrier();
  }

  // ---- cross-wave exchange of double coefficients (reuse Wp storage) ----
  __syncthreads();
  double* red = (double*)&Wp[0][0][0];   // 4*64*8 doubles = 16 KB < 64 KB
  {
    const int myrow = (ln >> 2) * 16 + quad * 4 + (ln & 3);
    double* rr = red + (size_t)(w * 64 + myrow) * 8;
    rr[0] = dAx; rr[1] = dIx; rr[2] = dMx; rr[3] = dQx;
    rr[4] = dAy; rr[5] = dIy; rr[6] = dMy; rr[7] = dQy;
  }
  __syncthreads();

  // ---- fused rejection sampler: one thread per row, exact JAX threefry ----
  if (tid < 64) {
    const int grow = r0 + tid;
    double Ax = 0, Ix = 0, Mx = 0, Qx = 0, Ay = 0, Iy = 0, My = 0, Qy = 0;
#pragma unroll
    for (int s = 0; s < 4; ++s) {
      const double* rr = red + (size_t)(s * 64 + tid) * 8;
      Ax += rr[0]; Ix += rr[1]; Mx += rr[2]; Qx += rr[3];
      Ay += rr[4]; Iy += rr[5]; My += rr[6]; Qy += rr[7];
    }

    U2 key = tf2x32(0u, 42u, 0u, (uint32_t)grow);   // partitionable split

    float xi = 0.0f;
    bool done = false;
    for (int it = 0; it < 100000 && !done; ++it) {
      const U2 kn = tf2x32(key.a, key.b, 0u, 0u);
      const U2 k1 = tf2x32(key.a, key.b, 0u, 1u);
      const U2 k2 = tf2x32(key.a, key.b, 0u, 2u);
      const U2 ru = tf2x32(k1.a, k1.b, 0u, 0u);
      const U2 rx = tf2x32(k2.a, k2.b, 0u, 0u);
      const float u  = bits_to_u01(ru.a ^ ru.b);
      const float u2 = bits_to_u01(rx.a ^ rx.b);
      xi = 2.0f * u2 - 1.0f;
      const double dxi = (double)xi;
      const double nx = (0.5 / 512.0) * (Ax + Qx + dxi * (dxi * Ix - 2.0 * Mx));
      const double ny = (0.5 / 512.0) * (Ay + Qy + dxi * (dxi * Iy - 2.0 * My));
      done = ((double)u >= nx * ny);
      key = kn;
    }
    out[grow] = fminf(fmaxf(xi, 1e-5f), 10.0f);
  }
}

// ---------------------------------------------------------------------------
// Fallback: R4's passing fp32-vector kernel (used only if ws_size < 4 MB).
// ---------------------------------------------------------------------------
__global__ __launch_bounds__(256, 1)
void fused_proposal_vec(const float* __restrict__ gx, const float* __restrict__ gy,
                        const float* __restrict__ Wmux, const float* __restrict__ bmux,
                        const float* __restrict__ Wsgx, const float* __restrict__ bsgx,
                        const float* __restrict__ Wmuy, const float* __restrict__ bmuy,
                        const float* __restrict__ Wsgy, const float* __restrict__ bsgy,
                        float* __restrict__ out)
{
  __shared__ float Xs[16][68];
  __shared__ float Wms[16][132];
  __shared__ float Wss[16][132];
  __shared__ double red[64][8];

  const int tid = threadIdx.x;
  const int tx = tid & 15;
  const int ty = tid >> 4;
  const int r0 = blockIdx.x * 64;
  const int lr = tid >> 2;
  const int q4 = (tid & 3) << 2;

  for (int i = tid; i < 64 * 8; i += 256) ((double*)red)[i] = 0.0;

  for (int ph = 0; ph < 8; ++ph) {
    const int dist = ph >> 2;
    const int c0 = (ph & 3) * 128;
    const float* __restrict__ Xg = dist ? gy : gx;
    const float* __restrict__ Wm = dist ? Wmuy : Wmux;
    const float* __restrict__ Wv = dist ? Wsgy : Wsgx;
    const float* __restrict__ bm = dist ? bmuy : bmux;
    const float* __restrict__ bv = dist ? bsgy : bsgx;

    float am[4][8], av[4][8];
#pragma unroll
    for (int r = 0; r < 4; ++r)
#pragma unroll
      for (int c = 0; c < 8; ++c) { am[r][c] = 0.0f; av[r][c] = 0.0f; }

    const float* xp  = Xg + (size_t)(r0 + lr) * 512 + q4;
    const float* mp0 = Wm + (size_t)(c0 + lr) * 512 + q4;
    const float* mp1 = Wm + (size_t)(c0 + lr + 64) * 512 + q4;
    const float* vp0 = Wv + (size_t)(c0 + lr) * 512 + q4;
    const float* vp1 = Wv + (size_t)(c0 + lr + 64) * 512 + q4;

    float4 xa = *(const float4*)(xp);
    float4 ma = *(const float4*)(mp0);
    float4 mb = *(const float4*)(mp1);
    float4 va = *(const float4*)(vp0);
    float4 vb = *(const float4*)(vp1);

    for (int t = 0; t < 32; ++t) {
      __syncthreads();
#define ST4(arr, col, v) { arr[q4+0][col]=v.x; arr[q4+1][col]=v.y; arr[q4+2][col]=v.z; arr[q4+3][col]=v.w; }
      ST4(Xs,  lr, xa)
      ST4(Wms, lr, ma)  ST4(Wms, lr + 64, mb)
      ST4(Wss, lr, va)  ST4(Wss, lr + 64, vb)
#undef ST4
      __syncthreads();
      if (t + 1 < 32) {
        const int ko = (t + 1) * 16;
        xa = *(const float4*)(xp + ko);
        ma = *(const float4*)(mp0 + ko);
        mb = *(const float4*)(mp1 + ko);
        va = *(const float4*)(vp0 + ko);
        vb = *(const float4*)(vp1 + ko);
      }
#pragma unroll
      for (int kk = 0; kk < 16; ++kk) {
        const float4 x0 = *(const float4*)&Xs[kk][ty * 4];
        const float4 m0 = *(const float4*)&Wms[kk][tx * 4];
        const float4 m1 = *(const float4*)&Wms[kk][tx * 4 + 64];
        const float4 v0 = *(const float4*)&Wss[kk][tx * 4];
        const float4 v1 = *(const float4*)&Wss[kk][tx * 4 + 64];
        const float xr[4] = {x0.x, x0.y, x0.z, x0.w};
        const float wm[8] = {m0.x, m0.y, m0.z, m0.w, m1.x, m1.y, m1.z, m1.w};
        const float wv[8] = {v0.x, v0.y, v0.z, v0.w, v1.x, v1.y, v1.z, v1.w};
#pragma unroll
        for (int r = 0; r < 4; ++r)
#pragma unroll
          for (int c = 0; c < 8; ++c) {
            am[r][c] = fmaf(xr[r], wm[c], am[r][c]);
            av[r][c] = fmaf(xr[r], wv[c], av[r][c]);
          }
      }
    }

    float bmr[8], bvr[8];
#pragma unroll
    for (int c = 0; c < 4; ++c) {
      bmr[c]     = bm[c0 + tx * 4 + c];
      bmr[4 + c] = bm[c0 + 64 + tx * 4 + c];
      bvr[c]     = bv[c0 + tx * 4 + c];
      bvr[4 + c] = bv[c0 + 64 + tx * 4 + c];
    }
#pragma unroll
    for (int r = 0; r < 4; ++r) {
      float pA = 0.f, pI = 0.f, pM = 0.f, pQ = 0.f;
#pragma unroll
      for (int c = 0; c < 8; ++c) {
        const float m = am[r][c] + bmr[c];
        const float s = av[r][c] + bvr[c];
        const float v = fmaxf(expf(s), 1e-6f);
        const float lg = fmaxf(s, LOG_EPS);
        const float inv = __builtin_amdgcn_rcpf(v);
        pA += lg; pI += inv; pM += m * inv; pQ += m * m * inv;
      }
#pragma unroll
      for (int msk = 1; msk < 16; msk <<= 1) {
        pA += __shfl_xor(pA, msk);
        pI += __shfl_xor(pI, msk);
        pM += __shfl_xor(pM, msk);
        pQ += __shfl_xor(pQ, msk);
      }
      if (tx == 0) {
        double* rr = &red[ty * 4 + r][dist * 4];
        rr[0] += (double)pA; rr[1] += (double)pI;
        rr[2] += (double)pM; rr[3] += (double)pQ;
      }
    }
  }

  __syncthreads();

  if (tid < 64) {
    const int grow = r0 + tid;
    const double Ax = red[tid][0], Ix = red[tid][1], Mx = red[tid][2], Qx = red[tid][3];
    const double Ay = red[tid][4], Iy = red[tid][5], My = red[tid][6], Qy = red[tid][7];
    U2 key = tf2x32(0u, 42u, 0u, (uint32_t)grow);
    float xi = 0.0f;
    bool done = false;
    for (int it = 0; it < 100000 && !done; ++it) {
      const U2 kn = tf2x32(key.a, key.b, 0u, 0u);
      const U2 k1 = tf2x32(key.a, key.b, 0u, 1u);
      const U2 k2 = tf2x32(key.a, key.b, 0u, 2u);
      const U2 ru = tf2x32(k1.a, k1.b, 0u, 0u);
      const U2 rx = tf2x32(k2.a, k2.b, 0u, 0u);
      const float u  = bits_to_u01(ru.a ^ ru.b);
      const float u2 = bits_to_u01(rx.a ^ rx.b);
      xi = 2.0f * u2 - 1.0f;
      const double dxi = (double)xi;
      const double nx = (0.5 / 512.0) * (Ax + Qx + dxi * (dxi * Ix - 2.0 * Mx));
      const double ny = (0.5 / 512.0) * (Ay + Qy + dxi * (dxi * Iy - 2.0 * My));
      done = ((double)u >= nx * ny);
      key = kn;
    }
    out[grow] = fminf(fmaxf(xi, 1e-5f), 10.0f);
  }
}

extern "C" void kernel_launch(void* const* d_in, const int* in_sizes, int n_in,
                              void* d_out, int out_size, void* d_ws, size_t ws_size,
                              hipStream_t stream) {
  const float* x    = (const float*)d_in[0];
  const float* y    = (const float*)d_in[1];
  const float* Wmux = (const float*)d_in[2];
  const float* bmux = (const float*)d_in[3];
  const float* Wsgx = (const float*)d_in[4];
  const float* bsgx = (const float*)d_in[5];
  const float* Wmuy = (const float*)d_in[6];
  const float* bmuy = (const float*)d_in[7];
  const float* Wsgy = (const float*)d_in[8];
  const float* bsgy = (const float*)d_in[9];
  (void)in_sizes; (void)n_in; (void)out_size;

  if (ws_size >= (size_t)WS_NEED) {
    convert_w_kernel<<<1024, 256, 0, stream>>>(Wmux, Wsgx, Wmuy, Wsgy, (f16*)d_ws);
    mfma_proposal_kernel<<<512, 256, 0, stream>>>(
        x, y, bmux, bsgx, bmuy, bsgy, (const f16*)d_ws, (float*)d_out);
  } else {
    fused_proposal_vec<<<512, 256, 0, stream>>>(
        x, y, Wmux, bmux, Wsgx, bsgx, Wmuy, bmuy, Wsgy, bsgy, (float*)d_out);
  }
}

// Round 2
// 367.779 us; speedup vs baseline: 1.1700x; 1.1700x over previous
//
#include <hip/hip_runtime.h>
#include <stdint.h>
#include <math.h>

// ============================================================================
// ProposalDistribution: 4x fp32 GEMM [32768,512]x[512,512]^T -> exp ->
// per-row Gaussian-NLL quadratic coefficients -> JAX-threefry rejection sampler.
//
// R7 -> R8: R7's explicit dbuf + asm waits regressed (348us vs R6 308us) —
// m141-style order-pinning; m114's implicit 2-blocks/CU overlap already hid
// the DMA latency. R8 reverts to R6's exact round/barrier structure and
// instead removes the W LDS path entirely: W has ZERO LDS reuse (each byte
// read once by one wave), and FETCH_SIZE proves W is L2-resident. W is
// pre-tiled into MFMA-fragment-major order (lane*16B -> perfectly coalesced
// global_load_dwordx4) and loaded straight to VGPRs, register-double-buffered
// one round ahead (explicit unroll-by-2, named reg sets). LDS port traffic
// per CU-round drops 208KB -> 80KB. X staging / epilogue / sampler are R6's
// bit-identical code.
// ============================================================================

typedef _Float16 f16;
typedef __attribute__((ext_vector_type(8))) _Float16 f16x8;
typedef __attribute__((ext_vector_type(4))) float f32x4;

#define SX 16.0f
#define SW 1024.0f
#define INV_S (1.0f / 16384.0f)
#define LOG_EPS (-13.815510557964274f)   // log(1e-6)
#define PLANE 262144                      // 512*512 elements per f16 plane
#define WS_NEED (4u * 2u * PLANE * 2u)    // 4 mats x (hi+lo) x 2B = 4 MB

// fragment-major W layout strides (f16 units):
// ws[mat(4)][hilo(2)][cg(4)][wv(4)][cj(2)][kc(16)][lane(64)][8]
// mat = dist*2 + (0=mu,1=sg)
#define KC_S   512
#define CJ_S   8192
#define WV_S   16384
#define CG_S   65536
#define HILO_S 262144
#define MAT_S  524288

struct U2 { uint32_t a, b; };

__device__ __forceinline__ uint32_t rotl(uint32_t v, int d) {
  return (v << d) | (v >> (32 - d));
}

// Threefry-2x32, 20 rounds — exact JAX algorithm.
__device__ __forceinline__ U2 tf2x32(uint32_t k0, uint32_t k1, uint32_t x0, uint32_t x1) {
  const uint32_t k2 = k0 ^ k1 ^ 0x1BD11BDAu;
  x0 += k0; x1 += k1;
#define TFR(r) { x0 += x1; x1 = rotl(x1, r); x1 ^= x0; }
  TFR(13) TFR(15) TFR(26) TFR(6)
  x0 += k1; x1 += k2 + 1u;
  TFR(17) TFR(29) TFR(16) TFR(24)
  x0 += k2; x1 += k0 + 2u;
  TFR(13) TFR(15) TFR(26) TFR(6)
  x0 += k0; x1 += k1 + 3u;
  TFR(17) TFR(29) TFR(16) TFR(24)
  x0 += k1; x1 += k2 + 4u;
  TFR(13) TFR(15) TFR(26) TFR(6)
  x0 += k2; x1 += k0 + 5u;
#undef TFR
  U2 r; r.a = x0; r.b = x1; return r;
}

__device__ __forceinline__ float bits_to_u01(uint32_t b) {
  return __uint_as_float((b >> 9) | 0x3f800000u) - 1.0f;
}

// ---------------------------------------------------------------------------
// Pre-kernel: split 4 W matrices (fp32, scaled by 1024) into f16 hi/lo planes,
// tiled in MFMA-fragment-major order so the main kernel's per-wave fragment
// load is one coalesced global_load_dwordx4 (lane*16B contiguous).
// Thread t handles 8 input floats: (mat, cg, wv, cj, kc, lane).
// Grid: 512 blocks x 256 threads = 131072 = 4 mats x 32768 chunks.
// ---------------------------------------------------------------------------
__global__ __launch_bounds__(256) void convert_w_kernel(
    const float* __restrict__ w0, const float* __restrict__ w1,
    const float* __restrict__ w2, const float* __restrict__ w3,
    f16* __restrict__ ws)
{
  const int t = blockIdx.x * 256 + threadIdx.x;
  const int mat = t >> 15;
  const int r = t & 32767;
  const int lane = r & 63;
  const int kc = (r >> 6) & 15;
  const int cj = (r >> 10) & 1;
  const int wv = (r >> 11) & 3;
  const int cg = (r >> 13) & 3;
  const int ln = lane & 15, quad = lane >> 4;
  const int row = cg * 128 + wv * 32 + cj * 16 + ln;   // output-feature index
  const int k0 = kc * 32 + quad * 8;                   // k index
  const float* W = (mat == 0) ? w0 : (mat == 1) ? w1 : (mat == 2) ? w2 : w3;
  const float* p = W + (size_t)row * 512 + k0;
  const float4 va = *(const float4*)p;
  const float4 vb = *(const float4*)(p + 4);
  const float a[8] = {va.x, va.y, va.z, va.w, vb.x, vb.y, vb.z, vb.w};
  f16x8 h, l;
#pragma unroll
  for (int i = 0; i < 8; ++i) {
    const float ai = a[i] * SW;
    const f16 hi = (f16)ai;
    h[i] = hi;
    l[i] = (f16)(ai - (float)hi);
  }
  f16* dst = ws + (size_t)mat * MAT_S + (size_t)cg * CG_S + (size_t)wv * WV_S
                + (size_t)cj * CJ_S + (size_t)kc * KC_S + (size_t)lane * 8;
  *(f16x8*)dst = h;
  *(f16x8*)(dst + HILO_S) = l;
}

// swizzled element offset within a [row][32] f16 LDS plane (X tile)
__device__ __forceinline__ int swz_off(int row, int quad) {
  return row * 32 + ((quad ^ ((row >> 1) & 3)) << 3);
}

// ---------------------------------------------------------------------------
// Main MFMA kernel. 512 blocks x 256 threads (4 waves), 2 blocks/CU.
// Block tile: 64 rows; per round: 128 cols x 32 k, both mats, one dist.
// Rounds ordered dist(2) -> colgroup(4) -> kchunk(16) = 128 rounds.
// Wave w computes cols w*32..+32 (2 col-frags) x 64 rows (4 row-frags).
// W fragments: direct global->VGPR (L2-resident, fragment-major layout),
// register-double-buffered one round ahead. X staged in LDS (R6 structure,
// two __syncthreads per round, compiler-managed waitcnts).
// ---------------------------------------------------------------------------
__global__ __launch_bounds__(256, 2)
void mfma_proposal_kernel(const float* __restrict__ gx, const float* __restrict__ gy,
                          const float* __restrict__ bmux, const float* __restrict__ bsgx,
                          const float* __restrict__ bmuy, const float* __restrict__ bsgy,
                          const f16* __restrict__ ws, float* __restrict__ out)
{
  __shared__ f16 Xh[64 * 32], Xl[64 * 32];   // [row][32k] swizzled, 8 KB
  __shared__ double red[4][64][8];           // per-wave coefficient slices, 16 KB

  const int tid = threadIdx.x;
  const int lane = tid & 63;
  const int w = tid >> 6;           // wave id
  const int ln = lane & 15;
  const int quad = lane >> 4;
  const int r0 = blockIdx.x * 64;

  const int xrow = tid >> 2;        // 0..63
  const int xs4 = tid & 3;          // k-seg for X staging
  const int xslot = (xs4 ^ ((xrow >> 1) & 3)) << 3;   // swizzled X store slot

  for (int i = tid; i < 4 * 64 * 8; i += 256) (&red[0][0][0])[i] = 0.0;

  // this wave's fragment base in the fragment-major W tiling
  const f16* wbase = ws + (size_t)w * WV_S + (size_t)lane * 8;

  float4 xr0, xr1;
  auto load_xr = [&](int n) {
    const float* Xg = (n >> 6) ? gy : gx;
    const float* xp = Xg + (size_t)(r0 + xrow) * 512 + (n & 15) * 32 + xs4 * 8;
    xr0 = *(const float4*)(xp);
    xr1 = *(const float4*)(xp + 4);
  };

  auto write_x = [&]() {
    float a0 = xr0.x * SX, a1 = xr0.y * SX, a2 = xr0.z * SX, a3 = xr0.w * SX;
    float a4 = xr1.x * SX, a5 = xr1.y * SX, a6 = xr1.z * SX, a7 = xr1.w * SX;
    f16 h0 = (f16)a0, h1 = (f16)a1, h2 = (f16)a2, h3 = (f16)a3;
    f16 h4 = (f16)a4, h5 = (f16)a5, h6 = (f16)a6, h7 = (f16)a7;
    *(f16x8*)&Xh[xrow * 32 + xslot] = (f16x8){h0, h1, h2, h3, h4, h5, h6, h7};
    *(f16x8*)&Xl[xrow * 32 + xslot] =
        (f16x8){(f16)(a0 - (float)h0), (f16)(a1 - (float)h1),
                (f16)(a2 - (float)h2), (f16)(a3 - (float)h3),
                (f16)(a4 - (float)h4), (f16)(a5 - (float)h5),
                (f16)(a6 - (float)h6), (f16)(a7 - (float)h7)};
  };

  // load round n's 8 W fragments (4 planes x 2 cj) straight to VGPRs.
  // planes: 0=mu-hi, 1=mu-lo, 2=sg-hi, 3=sg-lo.
  auto load_W = [&](int n, f16x8 (&B)[4][2]) {
    const int kc = n & 15, cg = (n >> 4) & 3, d = n >> 6;
    const f16* base = wbase + (size_t)(d * 2) * MAT_S + (size_t)cg * CG_S
                            + (size_t)kc * KC_S;
#pragma unroll
    for (int p = 0; p < 4; ++p)
#pragma unroll
      for (int cj = 0; cj < 2; ++cj)
        B[p][cj] = *(const f16x8*)(base + (size_t)(p >> 1) * MAT_S
                                        + (size_t)(p & 1) * HILO_S
                                        + (size_t)cj * CJ_S);
  };

  f16x8 Ba[4][2], Bb[4][2];
  f32x4 accm[4][2], accv[4][2];

  // prologue: X regs + W regs for round 0
  load_xr(0);
  load_W(0, Ba);

  auto round_fn = [&](int rid, f16x8 (&Bc)[4][2], f16x8 (&Bn)[4][2]) {
    const int kc = rid & 15;
    const int cg = (rid >> 4) & 3;
    const int dist = rid >> 6;

    if (kc == 0) {
#pragma unroll
      for (int ri = 0; ri < 4; ++ri)
#pragma unroll
        for (int cj = 0; cj < 2; ++cj) {
          accm[ri][cj] = (f32x4)0.0f;
          accv[ri][cj] = (f32x4)0.0f;
        }
    }

    __syncthreads();   // all waves done reading previous round's X
    write_x();         // xr holds round rid's X (prefetched last round)
    __syncthreads();   // X visible to all waves

    // prefetch next round: X regs + W regs (in flight through the MFMAs)
    if (rid + 1 < 128) {
      load_xr(rid + 1);
      load_W(rid + 1, Bn);
    }

    // ---- compute: 8 ds_read_b128 + 48 MFMAs per wave ----
    f16x8 ah[4], al[4];
#pragma unroll
    for (int ri = 0; ri < 4; ++ri) {
      const int off = swz_off(ri * 16 + ln, quad);
      ah[ri] = *(const f16x8*)&Xh[off];
      al[ri] = *(const f16x8*)&Xl[off];
    }
#pragma unroll
    for (int cj = 0; cj < 2; ++cj) {
      const f16x8 bhm = Bc[0][cj];
      const f16x8 blm = Bc[1][cj];
      const f16x8 bhv = Bc[2][cj];
      const f16x8 blv = Bc[3][cj];
#pragma unroll
      for (int ri = 0; ri < 4; ++ri) {
        accm[ri][cj] = __builtin_amdgcn_mfma_f32_16x16x32_f16(al[ri], bhm, accm[ri][cj], 0, 0, 0);
        accm[ri][cj] = __builtin_amdgcn_mfma_f32_16x16x32_f16(ah[ri], blm, accm[ri][cj], 0, 0, 0);
        accm[ri][cj] = __builtin_amdgcn_mfma_f32_16x16x32_f16(ah[ri], bhm, accm[ri][cj], 0, 0, 0);
        accv[ri][cj] = __builtin_amdgcn_mfma_f32_16x16x32_f16(al[ri], bhv, accv[ri][cj], 0, 0, 0);
        accv[ri][cj] = __builtin_amdgcn_mfma_f32_16x16x32_f16(ah[ri], blv, accv[ri][cj], 0, 0, 0);
        accv[ri][cj] = __builtin_amdgcn_mfma_f32_16x16x32_f16(ah[ri], bhv, accv[ri][cj], 0, 0, 0);
      }
    }

    // ---- epilogue per (dist, colgroup) ----
    if (kc == 15) {
      const float* bmu = dist ? bmuy : bmux;
      const float* bsg = dist ? bsgy : bsgx;
      float bm0 = bmu[cg * 128 + w * 32 + ln];
      float bm1 = bmu[cg * 128 + w * 32 + 16 + ln];
      float bv0 = bsg[cg * 128 + w * 32 + ln];
      float bv1 = bsg[cg * 128 + w * 32 + 16 + ln];
#pragma unroll
      for (int ri = 0; ri < 4; ++ri) {
#pragma unroll
        for (int g = 0; g < 4; ++g) {
          float pA = 0.f, pI = 0.f, pM = 0.f, pQ = 0.f;
#pragma unroll
          for (int cj = 0; cj < 2; ++cj) {
            const float m = accm[ri][cj][g] * INV_S + (cj ? bm1 : bm0);
            const float s = accv[ri][cj][g] * INV_S + (cj ? bv1 : bv0);
            const float vv = fmaxf(expf(s), 1e-6f);
            const float lg = fmaxf(s, LOG_EPS);
            const float iv = __builtin_amdgcn_rcpf(vv);
            pA += lg;
            pI += iv;
            pM += m * iv;
            pQ += m * m * iv;
          }
#pragma unroll
          for (int msk = 1; msk < 16; msk <<= 1) {
            pA += __shfl_xor(pA, msk);
            pI += __shfl_xor(pI, msk);
            pM += __shfl_xor(pM, msk);
            pQ += __shfl_xor(pQ, msk);
          }
          if (ln == 0) {
            double* rr = &red[w][ri * 16 + quad * 4 + g][dist * 4];
            rr[0] += (double)pA; rr[1] += (double)pI;
            rr[2] += (double)pM; rr[3] += (double)pQ;
          }
        }
      }
    }
  };

  // unroll-by-2 so the W register double-buffer uses only named sets
  for (int rr = 0; rr < 64; ++rr) {
    round_fn(rr * 2,     Ba, Bb);
    round_fn(rr * 2 + 1, Bb, Ba);
  }

  __syncthreads();

  // ---- fused rejection sampler: one thread per row, exact JAX threefry ----
  if (tid < 64) {
    const int grow = r0 + tid;
    double Ax = 0, Ix = 0, Mx = 0, Qx = 0, Ay = 0, Iy = 0, My = 0, Qy = 0;
#pragma unroll
    for (int s = 0; s < 4; ++s) {
      Ax += red[s][tid][0]; Ix += red[s][tid][1];
      Mx += red[s][tid][2]; Qx += red[s][tid][3];
      Ay += red[s][tid][4]; Iy += red[s][tid][5];
      My += red[s][tid][6]; Qy += red[s][tid][7];
    }

    U2 key = tf2x32(0u, 42u, 0u, (uint32_t)grow);   // partitionable split

    float xi = 0.0f;
    bool done = false;
    for (int it = 0; it < 100000 && !done; ++it) {
      const U2 kn = tf2x32(key.a, key.b, 0u, 0u);
      const U2 k1 = tf2x32(key.a, key.b, 0u, 1u);
      const U2 k2 = tf2x32(key.a, key.b, 0u, 2u);
      const U2 ru = tf2x32(k1.a, k1.b, 0u, 0u);
      const U2 rx = tf2x32(k2.a, k2.b, 0u, 0u);
      const float u  = bits_to_u01(ru.a ^ ru.b);
      const float u2 = bits_to_u01(rx.a ^ rx.b);
      xi = 2.0f * u2 - 1.0f;
      const double dxi = (double)xi;
      const double nx = (0.5 / 512.0) * (Ax + Qx + dxi * (dxi * Ix - 2.0 * Mx));
      const double ny = (0.5 / 512.0) * (Ay + Qy + dxi * (dxi * Iy - 2.0 * My));
      done = ((double)u >= nx * ny);
      key = kn;
    }
    out[grow] = fminf(fmaxf(xi, 1e-5f), 10.0f);
  }
}

// ---------------------------------------------------------------------------
// Fallback: R4's passing fp32-vector kernel (used only if ws_size < 4 MB).
// ---------------------------------------------------------------------------
__global__ __launch_bounds__(256, 1)
void fused_proposal_vec(const float* __restrict__ gx, const float* __restrict__ gy,
                        const float* __restrict__ Wmux, const float* __restrict__ bmux,
                        const float* __restrict__ Wsgx, const float* __restrict__ bsgx,
                        const float* __restrict__ Wmuy, const float* __restrict__ bmuy,
                        const float* __restrict__ Wsgy, const float* __restrict__ bsgy,
                        float* __restrict__ out)
{
  __shared__ float Xs[16][68];
  __shared__ float Wms[16][132];
  __shared__ float Wss[16][132];
  __shared__ double red[64][8];

  const int tid = threadIdx.x;
  const int tx = tid & 15;
  const int ty = tid >> 4;
  const int r0 = blockIdx.x * 64;
  const int lr = tid >> 2;
  const int q4 = (tid & 3) << 2;

  for (int i = tid; i < 64 * 8; i += 256) ((double*)red)[i] = 0.0;

  for (int ph = 0; ph < 8; ++ph) {
    const int dist = ph >> 2;
    const int c0 = (ph & 3) * 128;
    const float* __restrict__ Xg = dist ? gy : gx;
    const float* __restrict__ Wm = dist ? Wmuy : Wmux;
    const float* __restrict__ Wv = dist ? Wsgy : Wsgx;
    const float* __restrict__ bm = dist ? bmuy : bmux;
    const float* __restrict__ bv = dist ? bsgy : bsgx;

    float am[4][8], av[4][8];
#pragma unroll
    for (int r = 0; r < 4; ++r)
#pragma unroll
      for (int c = 0; c < 8; ++c) { am[r][c] = 0.0f; av[r][c] = 0.0f; }

    const float* xp  = Xg + (size_t)(r0 + lr) * 512 + q4;
    const float* mp0 = Wm + (size_t)(c0 + lr) * 512 + q4;
    const float* mp1 = Wm + (size_t)(c0 + lr + 64) * 512 + q4;
    const float* vp0 = Wv + (size_t)(c0 + lr) * 512 + q4;
    const float* vp1 = Wv + (size_t)(c0 + lr + 64) * 512 + q4;

    float4 xa = *(const float4*)(xp);
    float4 ma = *(const float4*)(mp0);
    float4 mb = *(const float4*)(mp1);
    float4 va = *(const float4*)(vp0);
    float4 vb = *(const float4*)(vp1);

    for (int t = 0; t < 32; ++t) {
      __syncthreads();
#define ST4(arr, col, v) { arr[q4+0][col]=v.x; arr[q4+1][col]=v.y; arr[q4+2][col]=v.z; arr[q4+3][col]=v.w; }
      ST4(Xs,  lr, xa)
      ST4(Wms, lr, ma)  ST4(Wms, lr + 64, mb)
      ST4(Wss, lr, va)  ST4(Wss, lr + 64, vb)
#undef ST4
      __syncthreads();
      if (t + 1 < 32) {
        const int ko = (t + 1) * 16;
        xa = *(const float4*)(xp + ko);
        ma = *(const float4*)(mp0 + ko);
        mb = *(const float4*)(mp1 + ko);
        va = *(const float4*)(vp0 + ko);
        vb = *(const float4*)(vp1 + ko);
      }
#pragma unroll
      for (int kk = 0; kk < 16; ++kk) {
        const float4 x0 = *(const float4*)&Xs[kk][ty * 4];
        const float4 m0 = *(const float4*)&Wms[kk][tx * 4];
        const float4 m1 = *(const float4*)&Wms[kk][tx * 4 + 64];
        const float4 v0 = *(const float4*)&Wss[kk][tx * 4];
        const float4 v1 = *(const float4*)&Wss[kk][tx * 4 + 64];
        const float xr[4] = {x0.x, x0.y, x0.z, x0.w};
        const float wm[8] = {m0.x, m0.y, m0.z, m0.w, m1.x, m1.y, m1.z, m1.w};
        const float wv[8] = {v0.x, v0.y, v0.z, v0.w, v1.x, v1.y, v1.z, v1.w};
#pragma unroll
        for (int r = 0; r < 4; ++r)
#pragma unroll
          for (int c = 0; c < 8; ++c) {
            am[r][c] = fmaf(xr[r], wm[c], am[r][c]);
            av[r][c] = fmaf(xr[r], wv[c], av[r][c]);
          }
      }
    }

    float bmr[8], bvr[8];
#pragma unroll
    for (int c = 0; c < 4; ++c) {
      bmr[c]     = bm[c0 + tx * 4 + c];
      bmr[4 + c] = bm[c0 + 64 + tx * 4 + c];
      bvr[c]     = bv[c0 + tx * 4 + c];
      bvr[4 + c] = bv[c0 + 64 + tx * 4 + c];
    }
#pragma unroll
    for (int r = 0; r < 4; ++r) {
      float pA = 0.f, pI = 0.f, pM = 0.f, pQ = 0.f;
#pragma unroll
      for (int c = 0; c < 8; ++c) {
        const float m = am[r][c] + bmr[c];
        const float s = av[r][c] + bvr[c];
        const float v = fmaxf(expf(s), 1e-6f);
        const float lg = fmaxf(s, LOG_EPS);
        const float inv = __builtin_amdgcn_rcpf(v);
        pA += lg; pI += inv; pM += m * inv; pQ += m * m * inv;
      }
#pragma unroll
      for (int msk = 1; msk < 16; msk <<= 1) {
        pA += __shfl_xor(pA, msk);
        pI += __shfl_xor(pI, msk);
        pM += __shfl_xor(pM, msk);
        pQ += __shfl_xor(pQ, msk);
      }
      if (tx == 0) {
        double* rr = &red[ty * 4 + r][dist * 4];
        rr[0] += (double)pA; rr[1] += (double)pI;
        rr[2] += (double)pM; rr[3] += (double)pQ;
      }
    }
  }

  __syncthreads();

  if (tid < 64) {
    const int grow = r0 + tid;
    const double Ax = red[tid][0], Ix = red[tid][1], Mx = red[tid][2], Qx = red[tid][3];
    const double Ay = red[tid][4], Iy = red[tid][5], My = red[tid][6], Qy = red[tid][7];
    U2 key = tf2x32(0u, 42u, 0u, (uint32_t)grow);
    float xi = 0.0f;
    bool done = false;
    for (int it = 0; it < 100000 && !done; ++it) {
      const U2 kn = tf2x32(key.a, key.b, 0u, 0u);
      const U2 k1 = tf2x32(key.a, key.b, 0u, 1u);
      const U2 k2 = tf2x32(key.a, key.b, 0u, 2u);
      const U2 ru = tf2x32(k1.a, k1.b, 0u, 0u);
      const U2 rx = tf2x32(k2.a, k2.b, 0u, 0u);
      const float u  = bits_to_u01(ru.a ^ ru.b);
      const float u2 = bits_to_u01(rx.a ^ rx.b);
      xi = 2.0f * u2 - 1.0f;
      const double dxi = (double)xi;
      const double nx = (0.5 / 512.0) * (Ax + Qx + dxi * (dxi * Ix - 2.0 * Mx));
      const double ny = (0.5 / 512.0) * (Ay + Qy + dxi * (dxi * Iy - 2.0 * My));
      done = ((double)u >= nx * ny);
      key = kn;
    }
    out[grow] = fminf(fmaxf(xi, 1e-5f), 10.0f);
  }
}

extern "C" void kernel_launch(void* const* d_in, const int* in_sizes, int n_in,
                              void* d_out, int out_size, void* d_ws, size_t ws_size,
                              hipStream_t stream) {
  const float* x    = (const float*)d_in[0];
  const float* y    = (const float*)d_in[1];
  const float* Wmux = (const float*)d_in[2];
  const float* bmux = (const float*)d_in[3];
  const float* Wsgx = (const float*)d_in[4];
  const float* bsgx = (const float*)d_in[5];
  const float* Wmuy = (const float*)d_in[6];
  const float* bmuy = (const float*)d_in[7];
  const float* Wsgy = (const float*)d_in[8];
  const float* bsgy = (const float*)d_in[9];
  (void)in_sizes; (void)n_in; (void)out_size;

  if (ws_size >= (size_t)WS_NEED) {
    convert_w_kernel<<<512, 256, 0, stream>>>(Wmux, Wsgx, Wmuy, Wsgy, (f16*)d_ws);
    mfma_proposal_kernel<<<512, 256, 0, stream>>>(
        x, y, bmux, bsgx, bmuy, bsgy, (const f16*)d_ws, (float*)d_out);
  } else {
    fused_proposal_vec<<<512, 256, 0, stream>>>(
        x, y, Wmux, bmux, Wsgx, bsgx, Wmuy, bmuy, Wsgy, bsgy, (float*)d_out);
  }
}